// Round 12
// baseline (267.428 us; speedup 1.0000x reference)
//
#include <hip/hip_runtime.h>

typedef __attribute__((ext_vector_type(8))) short bf16x8;
typedef __attribute__((ext_vector_type(4))) float f32x4;

#define LOG2E 1.44269504088896340736f

// Average-trace constant from the Python module (length 120).
__device__ __constant__ float AVG_D[120] = {
    0.0256f,0.0823f,0.1157f,0.1315f,0.1366f,0.1369f,0.1347f,0.1308f,0.1259f,0.1205f,
    0.1146f,0.1086f,0.1028f,0.0970f,0.0913f,0.0858f,0.0805f,0.0756f,0.0708f,0.0664f,
    0.0623f,0.0584f,0.0549f,0.0515f,0.0485f,0.0456f,0.0429f,0.0404f,0.0381f,0.0360f,
    0.0340f,0.0321f,0.0304f,0.0287f,0.0272f,0.0258f,0.0245f,0.0233f,0.0222f,0.0211f,
    0.0201f,0.0191f,0.0182f,0.0173f,0.0165f,0.0158f,0.0150f,0.0143f,0.0137f,0.0130f,
    0.0125f,0.0119f,0.0114f,0.0108f,0.0104f,0.0099f,0.0095f,0.0091f,0.0087f,0.0083f,
    0.0080f,0.0077f,0.0074f,0.0071f,0.0068f,0.0065f,0.0062f,0.0060f,0.0058f,0.0055f,
    0.0053f,0.0050f,0.0049f,0.0047f,0.0045f,0.0044f,0.0042f,0.0040f,0.0039f,0.0038f,
    0.0036f,0.0034f,0.0033f,0.0032f,0.0031f,0.0030f,0.0029f,0.0028f,0.0027f,0.0026f,
    0.0025f,0.0024f,0.0023f,0.0022f,0.0021f,0.0021f,0.0020f,0.0019f,0.0018f,0.0018f,
    0.0017f,0.0017f,0.0016f,0.0016f,0.0015f,0.0015f,0.0014f,0.0014f,0.0013f,0.0013f,
    0.0013f,0.0012f,0.0012f,0.0011f,0.0011f,0.0011f,0.0010f,0.0010f,0.0010f,0.0009f
};

__device__ __forceinline__ float sig2(float x) {
    return __builtin_amdgcn_rcpf(1.0f + __builtin_amdgcn_exp2f(x));
}
__device__ __forceinline__ float tanh2(float x) {
    return fmaf(2.0f, __builtin_amdgcn_rcpf(1.0f + __builtin_amdgcn_exp2f(x)), -1.0f);
}
__device__ __forceinline__ unsigned short tb(float x) {          // truncate fp32 -> bf16
    return (unsigned short)(__float_as_uint(x) >> 16);
}
__device__ __forceinline__ float fb(unsigned short h) {
    return __uint_as_float(((unsigned)h) << 16);
}

// A[128 rows][32 k], row r = u*4+q, PRE-SCALED by sc(q) = -log2e (i,f,o) / -2log2e (g):
//   u<30,  k<30 : sc*W_hh1[(q*30+u)*30+k]
//   u<30,  k==30: sc*W_ih1[(q*30+u)*13+12]   (avg column; B k=30 slot = AVG[t])
//   u==30, k<30 : sc*W_ih2[q*30+k]           (LSTM2 input dot rides the same MFMA)
// ws layout (float*): ushort whi[4096] @0; ushort wlo @2048; float bconst[128] @4096
//                     float wih1f[128*12] @4224; u32 avgpk[121] @5760 (hi|lo<<16)
__global__ void pack_weights(const float* __restrict__ w_ih1,
                             const float* __restrict__ w_hh1,
                             const float* __restrict__ b1,
                             const float* __restrict__ w_ih2,
                             const float* __restrict__ b2,
                             float* __restrict__ ws) {
    unsigned short* whi = (unsigned short*)ws;
    unsigned short* wlo = (unsigned short*)(ws + 2048);
    float* bconst = ws + 4096;
    float* wih1f  = ws + 4224;
    unsigned* avgpk = (unsigned*)(ws + 5760);
    const int tid = threadIdx.x;
    for (int idx = tid; idx < 4096; idx += 256) {
        const int T = idx >> 9, lane = (idx >> 3) & 63, j = idx & 7;
        const int r = 16 * T + (lane & 15);
        const int k = ((lane >> 4) & 3) * 8 + j;
        const int u = r >> 2, q = r & 3;
        const float sc = (q == 2) ? (-2.0f * LOG2E) : (-LOG2E);
        float v = 0.0f;
        if (u < 30) {
            if (k < 30)       v = w_hh1[(q * 30 + u) * 30 + k];
            else if (k == 30) v = w_ih1[(q * 30 + u) * 13 + 12];
        } else if (u == 30 && k < 30) {
            v = w_ih2[q * 30 + k];
        }
        v *= sc;
        const unsigned short hi = tb(v);
        whi[idx] = hi;
        wlo[idx] = tb(v - fb(hi));
    }
    for (int r = tid; r < 128; r += 256) {
        const int u = r >> 2, q = r & 3;
        const float sc = (q == 2) ? (-2.0f * LOG2E) : (-LOG2E);
        bconst[r] = sc * ((u < 30) ? b1[q * 30 + u] : ((u == 30) ? b2[q] : 0.0f));
    }
    for (int idx = tid; idx < 1536; idx += 256) {
        const int r = idx / 12, d = idx % 12;
        const int u = r >> 2, q = r & 3;
        const float sc = (q == 2) ? (-2.0f * LOG2E) : (-LOG2E);
        wih1f[idx] = (u < 30) ? sc * w_ih1[(q * 30 + u) * 13 + d] : 0.0f;
    }
    for (int t = tid; t < 121; t += 256) {
        const float a = (t < 120) ? AVG_D[t] : 0.0f;
        const unsigned short hi = tb(a);
        const unsigned short lo = tb(a - fb(hi));
        avgpk[t] = (unsigned)hi | ((unsigned)lo << 16);
    }
}

// R19: load-balanced 20/12 tile split on the R14 structure. Measured facts:
// idle ~60us is occupancy-INSENSITIVE (R14@4w 63us vs R17@8w 61us) — it's
// the lockstep barrier rendezvous. One measurable component: wave1 carried
// LSTM2 (+10 trans = ~220cyc/step) on top of an equal LSTM1 share; the
// barrier converts that straight into wave0 idle (~11us). Fix:
//   wave0 = tiles 0-4 (units 0-19, 25 trans/step)
//   wave1 = tiles 5-7 (units 20-31) + LSTM2 (15+10 = 25 trans/step)
// Plus: per-tile fused {3xMFMA trio -> gates} so tile T's trans issue under
// tile T+1's MFMA (smooths trans-pipe bursts); LSTM2 moved POST-barrier
// (overlaps next-step front); fmed3 clamp. Aggregate issue ~unchanged —
// this round attacks idle via balance, not issue.
// 2048 blocks x 128 thr, launch_bounds(128,4): VGPR cap 128 (est ~110).
__global__ __launch_bounds__(128, 4)
void lstm_mfma_kernel(const float* __restrict__ feat,
                      const float* __restrict__ w_hh2,
                      const float* __restrict__ ws,
                      float* __restrict__ out) {
    __shared__ __align__(16) unsigned short hhi[2][16 * 40];  // 2.5 KB x2 bufs
    __shared__ __align__(16) unsigned short hlo[2][16 * 40];  // 2.5 KB x2 bufs
    __shared__ __align__(16) float out_s[16 * 124];           // h2 staging 7.9 KB

    const int tid  = threadIdx.x;
    const int lane = tid & 63;
    const int wv   = __builtin_amdgcn_readfirstlane(tid >> 6) & 1;
    const int s    = lane & 15;
    const int quad = lane >> 4;
    const int seq  = blockIdx.x * 16 + s;
    const unsigned* avgpk = (const unsigned*)(ws + 5760);

    // zero both hi/lo buffers (pads stay 0)
    {
        unsigned* zh = (unsigned*)(&hhi[0][0]);
        unsigned* zl = (unsigned*)(&hlo[0][0]);
        for (int i = tid; i < 640; i += 128) { zh[i] = 0u; zl[i] = 0u; }
    }
    __syncthreads();
    if (tid < 16) {
        const unsigned a0 = avgpk[0];
        hhi[0][tid * 40 + 30] = (unsigned short)a0;          // hi half
        hlo[0][tid * 40 + 30] = (unsigned short)(a0 >> 16);  // lo half
    }

    // ---- A fragments: wave0 tiles 0-4, wave1 tiles 5-7 (local 0-2) ----
    const int NT = (wv == 0) ? 5 : 3;
    const int TB = (wv == 0) ? 0 : 5;
    bf16x8 Ahi[5], Alo[5];
    {
        const unsigned short* wahi = (const unsigned short*)ws;
        const unsigned short* walo = (const unsigned short*)(ws + 2048);
#pragma unroll
        for (int T = 0; T < 5; T++) {
            if (T < NT) {
                Ahi[T] = *(const bf16x8*)(wahi + (TB + T) * 512 + lane * 8);
                Alo[T] = *(const bf16x8*)(walo + (TB + T) * 512 + lane * 8);
            }
        }
    }

    // ---- per-sequence constant projection (scaled domain) ----
    float f0[12];
    {
        const float4* fp = reinterpret_cast<const float4*>(feat + seq * 12);
        float4 A = fp[0], B = fp[1], C = fp[2];
        f0[0]=A.x; f0[1]=A.y; f0[2]=A.z; f0[3]=A.w;
        f0[4]=B.x; f0[5]=B.y; f0[6]=B.z; f0[7]=B.w;
        f0[8]=C.x; f0[9]=C.y; f0[10]=C.z; f0[11]=C.w;
    }
    f32x4 projb[5];
    {
        const float* bconst = ws + 4096;
        const float* wih1f  = ws + 4224;
#pragma unroll
        for (int T = 0; T < 5; T++) {
            if (T < NT) {
#pragma unroll
                for (int g = 0; g < 4; g++) {
                    const int r = 16 * (TB + T) + 4 * quad + g;
                    float acc = bconst[r];
#pragma unroll
                    for (int d = 0; d < 12; d++) acc = fmaf(f0[d], wih1f[r * 12 + d], acc);
                    projb[T][g] = acc;
                }
            }
        }
    }

    float c1[5];
#pragma unroll
    for (int T = 0; T < 5; T++) c1[T] = 0.0f;
    float h2 = 0.0f, c2 = 0.0f;
    const float whs0 = -LOG2E * w_hh2[0];
    const float whs1 = -LOG2E * w_hh2[1];
    const float whs2 = -2.0f * LOG2E * w_hh2[2];
    const float whs3 = -LOG2E * w_hh2[3];

    __syncthreads();   // AVG seed visible to both waves

    unsigned apk_cur = avgpk[1];   // AVG slot value for the t=0 update

#define TRIO(Tl) ({ \
        f32x4 d_ = __builtin_amdgcn_mfma_f32_16x16x32_bf16(Alo[Tl], Bhi, projb[Tl], 0, 0, 0); \
        d_ = __builtin_amdgcn_mfma_f32_16x16x32_bf16(Ahi[Tl], Blo, d_, 0, 0, 0); \
        __builtin_amdgcn_mfma_f32_16x16x32_bf16(Ahi[Tl], Bhi, d_, 0, 0, 0); })

#define GATES(dv, Tl) do { \
        const float ei_ = __builtin_amdgcn_exp2f(dv[0]); \
        const float ef_ = __builtin_amdgcn_exp2f(dv[1]); \
        const float eg_ = __builtin_amdgcn_exp2f(dv[2]); \
        const float eo_ = __builtin_amdgcn_exp2f(dv[3]); \
        const float pf_ = 1.0f + ef_; \
        const float pig_ = (1.0f + ei_) * (1.0f + eg_); \
        const float num_ = fmaf(c1[Tl], pig_, (1.0f - eg_) * pf_); \
        const float ck_ = num_ * __builtin_amdgcn_rcpf(pf_ * pig_); \
        c1[Tl] = ck_; \
        const float carg_ = __builtin_amdgcn_fmed3f(-2.0f * LOG2E * ck_, -20.0f, 20.0f); \
        const float ec_ = __builtin_amdgcn_exp2f(carg_); \
        s2a[Tl] = 1.0f - ec_; \
        Ba[Tl]  = (1.0f + eo_) * (1.0f + ec_); \
    } while (0)

#define STOREH(hkv, u_) do { \
        const float hk_ = (hkv); \
        const unsigned hb_ = __float_as_uint(hk_); \
        const float rem_ = hk_ - __uint_as_float(hb_ & 0xffff0000u); \
        nh[s * 40 + (u_)] = (unsigned short)(hb_ >> 16); \
        nl[s * 40 + (u_)] = (unsigned short)(__float_as_uint(rem_) >> 16); \
    } while (0)

#pragma unroll 1
    for (int t = 0; t <= 120; t++) {
        const int buf = t & 1;
        const unsigned short* bh = hhi[buf];
        const unsigned short* bl = hlo[buf];
        unsigned short* nh = hhi[buf ^ 1];
        unsigned short* nl = hlo[buf ^ 1];

        // prefetch next AVG word a full iteration early (off the serial chain)
        const unsigned apk = apk_cur;
        apk_cur = avgpk[(t + 2 <= 120) ? (t + 2) : 120];

        // ---- B fragment: 2 direct ds_read_b128 ----
        const bf16x8 Bhi = *(const bf16x8*)(bh + s * 40 + 8 * quad);
        const bf16x8 Blo = *(const bf16x8*)(bl + s * 40 + 8 * quad);

        float s2a[5], Ba[5];
        f32x4 Dlast;

        if (wv == 0) {
            // ---- 5 tiles, fused trio->gates, pairs (0,1),(2,3), solo 4 ----
            f32x4 d0 = TRIO(0);
            if (t < 120) GATES(d0, 0);
            f32x4 d1 = TRIO(1);
            if (t < 120) {
                GATES(d1, 1);
                const float P = __builtin_amdgcn_rcpf(Ba[0] * Ba[1]);
                STOREH(s2a[0] * (Ba[1] * P), 0 + quad);
                STOREH(s2a[1] * (Ba[0] * P), 4 + quad);
            }
            f32x4 d2 = TRIO(2);
            if (t < 120) GATES(d2, 2);
            f32x4 d3 = TRIO(3);
            if (t < 120) {
                GATES(d3, 3);
                const float P = __builtin_amdgcn_rcpf(Ba[2] * Ba[3]);
                STOREH(s2a[2] * (Ba[3] * P), 8 + quad);
                STOREH(s2a[3] * (Ba[2] * P), 12 + quad);
            }
            f32x4 d4 = TRIO(4);
            if (t < 120) {
                GATES(d4, 4);
                STOREH(s2a[4] * __builtin_amdgcn_rcpf(Ba[4]), 16 + quad);
            }
        } else {
            // ---- 3 tiles (units 20-31) + LSTM2 row; pair (0,1), solo 2 ----
            f32x4 d0 = TRIO(0);
            if (t < 120) GATES(d0, 0);
            f32x4 d1 = TRIO(1);
            if (t < 120) {
                GATES(d1, 1);
                const float P = __builtin_amdgcn_rcpf(Ba[0] * Ba[1]);
                STOREH(s2a[0] * (Ba[1] * P), 20 + quad);
                STOREH(s2a[1] * (Ba[0] * P), 24 + quad);
            }
            Dlast = TRIO(2);
            if (t < 120) {
                GATES(Dlast, 2);
                const float hk = s2a[2] * __builtin_amdgcn_rcpf(Ba[2]);
                const unsigned hb = __float_as_uint(hk);
                const float rem = hk - __uint_as_float(hb & 0xffff0000u);
                unsigned hi16 = hb >> 16;
                unsigned lo16 = __float_as_uint(rem) >> 16;
                if (quad == 2) { hi16 = apk & 0xffffu; lo16 = apk >> 16; }       // u=30: AVG[t+1]
                else if (quad == 3) { hi16 = 0u; lo16 = 0u; }                    // u=31: pad
                nh[s * 40 + 28 + quad] = (unsigned short)hi16;
                nl[s * 40 + 28 + quad] = (unsigned short)lo16;
            }
        }

        if (t < 120) __syncthreads();   // h_t halves visible to both waves

        // ---- LSTM2 cell for step t-1 (POST-barrier: overlaps both waves'
        //      next-step front; Dlast = wave1 local tile2 = rows 120..123) ----
        if (wv == 1 && t >= 1 && quad == 2) {
            const float g0 = fmaf(h2, whs0, Dlast[0]);
            const float g1 = fmaf(h2, whs1, Dlast[1]);
            const float g2 = fmaf(h2, whs2, Dlast[2]);
            const float g3 = fmaf(h2, whs3, Dlast[3]);
            c2 = sig2(g1) * c2 + sig2(g0) * tanh2(g2);
            h2 = sig2(g3) * tanh2(c2 * (-2.0f * LOG2E));
            out_s[s * 124 + (t - 1)] = h2;
        }
    }

    __syncthreads();
    // ---- coalesced flush: 16 seq x 120 t = 480 float4 by 128 threads ----
    float* outb = out + (size_t)blockIdx.x * 16 * 120;
#pragma unroll
    for (int it = 0; it < 4; it++) {
        const int fi = it * 128 + tid;
        if (fi < 480) {
            const int sq = fi / 30, j = fi % 30;
            const float4 v = *reinterpret_cast<const float4*>(&out_s[sq * 124 + j * 4]);
            *reinterpret_cast<float4*>(&outb[sq * 120 + j * 4]) = v;
        }
    }
}

extern "C" void kernel_launch(void* const* d_in, const int* in_sizes, int n_in,
                              void* d_out, int out_size, void* d_ws, size_t ws_size,
                              hipStream_t stream) {
    (void)in_sizes; (void)n_in; (void)out_size; (void)ws_size;
    const float* feat  = (const float*)d_in[0];
    const float* w_ih1 = (const float*)d_in[1];
    const float* w_hh1 = (const float*)d_in[2];
    const float* b1    = (const float*)d_in[3];
    const float* w_ih2 = (const float*)d_in[4];
    const float* w_hh2 = (const float*)d_in[5];
    const float* b2    = (const float*)d_in[6];
    float* ws  = (float*)d_ws;
    float* out = (float*)d_out;

    hipLaunchKernelGGL(pack_weights, dim3(1), dim3(256), 0, stream,
                       w_ih1, w_hh1, b1, w_ih2, b2, ws);
    hipLaunchKernelGGL(lstm_mfma_kernel, dim3(2048), dim3(128), 0, stream,
                       feat, w_hh2, ws, out);
}

// Round 13
// 245.416 us; speedup vs baseline: 1.0897x; 1.0897x over previous
//
#include <hip/hip_runtime.h>

typedef __attribute__((ext_vector_type(8))) short bf16x8;
typedef __attribute__((ext_vector_type(4))) float f32x4;

#define LOG2E 1.44269504088896340736f

// Average-trace constant from the Python module (length 120).
__device__ __constant__ float AVG_D[120] = {
    0.0256f,0.0823f,0.1157f,0.1315f,0.1366f,0.1369f,0.1347f,0.1308f,0.1259f,0.1205f,
    0.1146f,0.1086f,0.1028f,0.0970f,0.0913f,0.0858f,0.0805f,0.0756f,0.0708f,0.0664f,
    0.0623f,0.0584f,0.0549f,0.0515f,0.0485f,0.0456f,0.0429f,0.0404f,0.0381f,0.0360f,
    0.0340f,0.0321f,0.0304f,0.0287f,0.0272f,0.0258f,0.0245f,0.0233f,0.0222f,0.0211f,
    0.0201f,0.0191f,0.0182f,0.0173f,0.0165f,0.0158f,0.0150f,0.0143f,0.0137f,0.0130f,
    0.0125f,0.0119f,0.0114f,0.0108f,0.0104f,0.0099f,0.0095f,0.0091f,0.0087f,0.0083f,
    0.0080f,0.0077f,0.0074f,0.0071f,0.0068f,0.0065f,0.0062f,0.0060f,0.0058f,0.0055f,
    0.0053f,0.0050f,0.0049f,0.0047f,0.0045f,0.0044f,0.0042f,0.0040f,0.0039f,0.0038f,
    0.0036f,0.0034f,0.0033f,0.0032f,0.0031f,0.0030f,0.0029f,0.0028f,0.0027f,0.0026f,
    0.0025f,0.0024f,0.0023f,0.0022f,0.0021f,0.0021f,0.0020f,0.0019f,0.0018f,0.0018f,
    0.0017f,0.0017f,0.0016f,0.0016f,0.0015f,0.0015f,0.0014f,0.0014f,0.0013f,0.0013f,
    0.0013f,0.0012f,0.0012f,0.0011f,0.0011f,0.0011f,0.0010f,0.0010f,0.0010f,0.0009f
};

__device__ __forceinline__ float sig2(float x) {
    return __builtin_amdgcn_rcpf(1.0f + __builtin_amdgcn_exp2f(x));
}
__device__ __forceinline__ float tanh2(float x) {
    return fmaf(2.0f, __builtin_amdgcn_rcpf(1.0f + __builtin_amdgcn_exp2f(x)), -1.0f);
}
__device__ __forceinline__ unsigned short tb(float x) {          // truncate fp32 -> bf16
    return (unsigned short)(__float_as_uint(x) >> 16);
}
__device__ __forceinline__ float fb(unsigned short h) {
    return __uint_as_float(((unsigned)h) << 16);
}

// A[128 rows][32 k], row r = u*4+q, PRE-SCALED by sc(q) = -log2e (i,f,o) / -2log2e (g):
//   u<30,  k<30 : sc*W_hh1[(q*30+u)*30+k]
//   u<30,  k==30: sc*W_ih1[(q*30+u)*13+12]   (avg column; B k=30 slot = AVG[t])
//   u==30, k<30 : sc*W_ih2[q*30+k]           (LSTM2 input dot rides the same MFMA)
// ws layout (float*): ushort whi[4096] @0; ushort wlo @2048; float bconst[128] @4096
//                     float wih1f[128*12] @4224; u32 avgpk[121] @5760 (hi|lo<<16)
__global__ void pack_weights(const float* __restrict__ w_ih1,
                             const float* __restrict__ w_hh1,
                             const float* __restrict__ b1,
                             const float* __restrict__ w_ih2,
                             const float* __restrict__ b2,
                             float* __restrict__ ws) {
    unsigned short* whi = (unsigned short*)ws;
    unsigned short* wlo = (unsigned short*)(ws + 2048);
    float* bconst = ws + 4096;
    float* wih1f  = ws + 4224;
    unsigned* avgpk = (unsigned*)(ws + 5760);
    const int tid = threadIdx.x;
    for (int idx = tid; idx < 4096; idx += 256) {
        const int T = idx >> 9, lane = (idx >> 3) & 63, j = idx & 7;
        const int r = 16 * T + (lane & 15);
        const int k = ((lane >> 4) & 3) * 8 + j;
        const int u = r >> 2, q = r & 3;
        const float sc = (q == 2) ? (-2.0f * LOG2E) : (-LOG2E);
        float v = 0.0f;
        if (u < 30) {
            if (k < 30)       v = w_hh1[(q * 30 + u) * 30 + k];
            else if (k == 30) v = w_ih1[(q * 30 + u) * 13 + 12];
        } else if (u == 30 && k < 30) {
            v = w_ih2[q * 30 + k];
        }
        v *= sc;
        const unsigned short hi = tb(v);
        whi[idx] = hi;
        wlo[idx] = tb(v - fb(hi));
    }
    for (int r = tid; r < 128; r += 256) {
        const int u = r >> 2, q = r & 3;
        const float sc = (q == 2) ? (-2.0f * LOG2E) : (-LOG2E);
        bconst[r] = sc * ((u < 30) ? b1[q * 30 + u] : ((u == 30) ? b2[q] : 0.0f));
    }
    for (int idx = tid; idx < 1536; idx += 256) {
        const int r = idx / 12, d = idx % 12;
        const int u = r >> 2, q = r & 3;
        const float sc = (q == 2) ? (-2.0f * LOG2E) : (-LOG2E);
        wih1f[idx] = (u < 30) ? sc * w_ih1[(q * 30 + u) * 13 + d] : 0.0f;
    }
    for (int t = tid; t < 121; t += 256) {
        const float a = (t < 120) ? AVG_D[t] : 0.0f;
        const unsigned short hi = tb(a);
        const unsigned short lo = tb(a - fb(hi));
        avgpk[t] = (unsigned)hi | ((unsigned)lo << 16);
    }
}

// R20 = exact revert to R14, the measured optimum (198.5us steady; VALUBusy
// 68%, MfmaUtil 21.3, VGPR 52, FETCH ~890KB). Post-R14 structural probes all
// regressed: R16 dual-group ILP 216.7 (same busy, more idle at 2w/SIMD),
// R17 4-wave split 205 (Occ 60% but idle unchanged — barrier-structural),
// R19 20/12 balance+fusion 219 (i-cache blowup: FETCH 890KB->4.7MB, busy
// +26us from fat divergent loop). Invariant: busy ~132-135us = trans-issue
// floor of this formulation (5 exp2 + ~1.5 rcp per cell @ ~16cyc/wave64);
// idle ~60us = per-step dependency/rendezvous shadow, insensitive to
// occupancy/ILP/balance. The compact symmetric branch-free inner loop IS
// the optimum found. Structure: 2 waves/block, wave w owns tiles 4w..4w+3
// (units 16w..16w+15; wave1 owns LSTM2 row u=30); hi/lo split LDS (stride
// 40 ushorts) -> B = 2 direct ds_read_b128, no perms; paired h-rcp with
// carg clamp +-20; unguarded cell math with store-patch for u>=30; one
// __syncthreads per step; avgpk prefetched one iter ahead.
__global__ __launch_bounds__(128, 4)
void lstm_mfma_kernel(const float* __restrict__ feat,
                      const float* __restrict__ w_hh2,
                      const float* __restrict__ ws,
                      float* __restrict__ out) {
    __shared__ __align__(16) unsigned short hhi[2][16 * 40];  // 2.5 KB x2 bufs
    __shared__ __align__(16) unsigned short hlo[2][16 * 40];  // 2.5 KB x2 bufs
    __shared__ __align__(16) float out_s[16 * 124];           // h2 staging 7.9 KB

    const int tid  = threadIdx.x;
    const int lane = tid & 63;
    const int wv   = __builtin_amdgcn_readfirstlane(tid >> 6) & 1;
    const int s    = lane & 15;
    const int quad = lane >> 4;
    const int seq  = blockIdx.x * 16 + s;
    const unsigned* avgpk = (const unsigned*)(ws + 5760);

    // zero both hi/lo buffers (pads stay 0)
    {
        unsigned* zh = (unsigned*)(&hhi[0][0]);
        unsigned* zl = (unsigned*)(&hlo[0][0]);
        for (int i = tid; i < 640; i += 128) { zh[i] = 0u; zl[i] = 0u; }
    }
    __syncthreads();
    if (tid < 16) {
        const unsigned a0 = avgpk[0];
        hhi[0][tid * 40 + 30] = (unsigned short)a0;          // hi half
        hlo[0][tid * 40 + 30] = (unsigned short)(a0 >> 16);  // lo half
    }

    // ---- A fragments: this wave's 4 tiles (Tg = 4*wv + T) ----
    bf16x8 Ahi[4], Alo[4];
    {
        const unsigned short* wahi = (const unsigned short*)ws;
        const unsigned short* walo = (const unsigned short*)(ws + 2048);
#pragma unroll
        for (int T = 0; T < 4; T++) {
            const int Tg = 4 * wv + T;
            Ahi[T] = *(const bf16x8*)(wahi + Tg * 512 + lane * 8);
            Alo[T] = *(const bf16x8*)(walo + Tg * 512 + lane * 8);
        }
    }

    // ---- per-sequence constant projection (scaled domain), 4 tiles ----
    float f0[12];
    {
        const float4* fp = reinterpret_cast<const float4*>(feat + seq * 12);
        float4 A = fp[0], B = fp[1], C = fp[2];
        f0[0]=A.x; f0[1]=A.y; f0[2]=A.z; f0[3]=A.w;
        f0[4]=B.x; f0[5]=B.y; f0[6]=B.z; f0[7]=B.w;
        f0[8]=C.x; f0[9]=C.y; f0[10]=C.z; f0[11]=C.w;
    }
    f32x4 projb[4];
    {
        const float* bconst = ws + 4096;
        const float* wih1f  = ws + 4224;
#pragma unroll
        for (int T = 0; T < 4; T++) {
#pragma unroll
            for (int g = 0; g < 4; g++) {
                const int r = 16 * (4 * wv + T) + 4 * quad + g;
                float acc = bconst[r];
#pragma unroll
                for (int d = 0; d < 12; d++) acc = fmaf(f0[d], wih1f[r * 12 + d], acc);
                projb[T][g] = acc;
            }
        }
    }

    float c1[4];
#pragma unroll
    for (int T = 0; T < 4; T++) c1[T] = 0.0f;
    float h2 = 0.0f, c2 = 0.0f;
    const float whs0 = -LOG2E * w_hh2[0];
    const float whs1 = -LOG2E * w_hh2[1];
    const float whs2 = -2.0f * LOG2E * w_hh2[2];
    const float whs3 = -LOG2E * w_hh2[3];

    __syncthreads();   // AVG seed visible to both waves

    unsigned apk_cur = avgpk[1];   // AVG slot value for the t=0 update

#pragma unroll 1
    for (int t = 0; t <= 120; t++) {
        const int buf = t & 1;
        const unsigned short* bh = hhi[buf];
        const unsigned short* bl = hlo[buf];
        unsigned short* nh = hhi[buf ^ 1];
        unsigned short* nl = hlo[buf ^ 1];

        // prefetch next AVG word a full iteration early (off the serial chain)
        const unsigned apk = apk_cur;
        apk_cur = avgpk[(t + 2 <= 120) ? (t + 2) : 120];

        // ---- B fragment: 2 direct ds_read_b128, NO perms ----
        const bf16x8 Bhi = *(const bf16x8*)(bh + s * 40 + 8 * quad);
        const bf16x8 Blo = *(const bf16x8*)(bl + s * 40 + 8 * quad);

        // ---- 12 MFMAs: D = Ahi*Bhi + Ahi*Blo + Alo*Bhi + projb ----
        f32x4 D[4];
#pragma unroll
        for (int T = 0; T < 4; T++)
            D[T] = __builtin_amdgcn_mfma_f32_16x16x32_bf16(Alo[T], Bhi, projb[T], 0, 0, 0);
#pragma unroll
        for (int T = 0; T < 4; T++)
            D[T] = __builtin_amdgcn_mfma_f32_16x16x32_bf16(Ahi[T], Blo, D[T], 0, 0, 0);
#pragma unroll
        for (int T = 0; T < 4; T++)
            D[T] = __builtin_amdgcn_mfma_f32_16x16x32_bf16(Ahi[T], Bhi, D[T], 0, 0, 0);

        // ---- LSTM2 cell for step t-1 (wave1 local tile3 = rows 120..123) ----
        if (wv == 1 && t >= 1 && quad == 2) {
            const float g0 = fmaf(h2, whs0, D[3][0]);
            const float g1 = fmaf(h2, whs1, D[3][1]);
            const float g2 = fmaf(h2, whs2, D[3][2]);
            const float g3 = fmaf(h2, whs3, D[3][3]);
            c2 = sig2(g1) * c2 + sig2(g0) * tanh2(g2);
            h2 = sig2(g3) * tanh2(c2 * (-2.0f * LOG2E));
            out_s[s * 124 + (t - 1)] = h2;
        }

        // ---- LSTM1 activations (u=16wv+4T+quad), UNGUARDED; paired h-rcp ----
        if (t < 120) {
            float s2a[4], Ba[4], hka[4];
#pragma unroll
            for (int T = 0; T < 4; T++) {
                const float ei = __builtin_amdgcn_exp2f(D[T][0]);
                const float ef = __builtin_amdgcn_exp2f(D[T][1]);
                const float eg = __builtin_amdgcn_exp2f(D[T][2]);
                const float eo = __builtin_amdgcn_exp2f(D[T][3]);
                const float pi_ = 1.0f + ei, pf = 1.0f + ef;
                const float pg  = 1.0f + eg, po = 1.0f + eo;
                const float pig = pi_ * pg;
                const float num = fmaf(c1[T], pig, (1.0f - eg) * pf);
                const float ck  = num * __builtin_amdgcn_rcpf(pf * pig);
                c1[T] = ck;
                float carg = -2.0f * LOG2E * ck;
                carg = fminf(fmaxf(carg, -20.0f), 20.0f);
                const float ec = __builtin_amdgcn_exp2f(carg);
                s2a[T] = 1.0f - ec;
                Ba[T]  = po * (1.0f + ec);
            }
            // paired reciprocals: (0,1) both always live; (2,3) T=3 may be dead
            {
                const float P01 = __builtin_amdgcn_rcpf(Ba[0] * Ba[1]);
                hka[0] = s2a[0] * (Ba[1] * P01);
                hka[1] = s2a[1] * (Ba[0] * P01);
                const int u3 = 16 * wv + 12 + quad;
                const float B3e = (u3 < 30) ? Ba[3] : 1.0f;
                const float P23 = __builtin_amdgcn_rcpf(Ba[2] * B3e);
                hka[2] = s2a[2] * (B3e * P23);
                hka[3] = s2a[3] * (Ba[2] * P23);
            }
#pragma unroll
            for (int T = 0; T < 4; T++) {
                const int u = 16 * wv + 4 * T + quad;
                const unsigned hbits = __float_as_uint(hka[T]);
                const float rem = hka[T] - __uint_as_float(hbits & 0xffff0000u);
                unsigned hi16 = hbits >> 16;
                unsigned lo16 = __float_as_uint(rem) >> 16;
                if (T == 3) {                       // only T=3 can hit u>=30
                    if (u == 30) { hi16 = apk & 0xffffu; lo16 = apk >> 16; }
                    else if (u == 31) { hi16 = 0u; lo16 = 0u; }
                }
                nh[s * 40 + u] = (unsigned short)hi16;
                nl[s * 40 + u] = (unsigned short)lo16;
            }
            __syncthreads();                        // h_t halves visible to both waves
        }
    }

    __syncthreads();
    // ---- coalesced flush: 16 seq x 120 t = 480 float4 by 128 threads ----
    float* outb = out + (size_t)blockIdx.x * 16 * 120;
#pragma unroll
    for (int it = 0; it < 4; it++) {
        const int fi = it * 128 + tid;
        if (fi < 480) {
            const int sq = fi / 30, j = fi % 30;
            const float4 v = *reinterpret_cast<const float4*>(&out_s[sq * 124 + j * 4]);
            *reinterpret_cast<float4*>(&outb[sq * 120 + j * 4]) = v;
        }
    }
}

extern "C" void kernel_launch(void* const* d_in, const int* in_sizes, int n_in,
                              void* d_out, int out_size, void* d_ws, size_t ws_size,
                              hipStream_t stream) {
    (void)in_sizes; (void)n_in; (void)out_size; (void)ws_size;
    const float* feat  = (const float*)d_in[0];
    const float* w_ih1 = (const float*)d_in[1];
    const float* w_hh1 = (const float*)d_in[2];
    const float* b1    = (const float*)d_in[3];
    const float* w_ih2 = (const float*)d_in[4];
    const float* w_hh2 = (const float*)d_in[5];
    const float* b2    = (const float*)d_in[6];
    float* ws  = (float*)d_ws;
    float* out = (float*)d_out;

    hipLaunchKernelGGL(pack_weights, dim3(1), dim3(256), 0, stream,
                       w_ih1, w_hh1, b1, w_ih2, b2, ws);
    hipLaunchKernelGGL(lstm_mfma_kernel, dim3(2048), dim3(128), 0, stream,
                       feat, w_hh2, ws, out);
}

// Round 16
// 238.065 us; speedup vs baseline: 1.1233x; 1.0309x over previous
//
#include <hip/hip_runtime.h>

typedef __attribute__((ext_vector_type(8))) short bf16x8;
typedef __attribute__((ext_vector_type(4))) float f32x4;

#define LOG2E 1.44269504088896340736f

// Average-trace constant from the Python module (length 120).
__device__ __constant__ float AVG_D[120] = {
    0.0256f,0.0823f,0.1157f,0.1315f,0.1366f,0.1369f,0.1347f,0.1308f,0.1259f,0.1205f,
    0.1146f,0.1086f,0.1028f,0.0970f,0.0913f,0.0858f,0.0805f,0.0756f,0.0708f,0.0664f,
    0.0623f,0.0584f,0.0549f,0.0515f,0.0485f,0.0456f,0.0429f,0.0404f,0.0381f,0.0360f,
    0.0340f,0.0321f,0.0304f,0.0287f,0.0272f,0.0258f,0.0245f,0.0233f,0.0222f,0.0211f,
    0.0201f,0.0191f,0.0182f,0.0173f,0.0165f,0.0158f,0.0150f,0.0143f,0.0137f,0.0130f,
    0.0125f,0.0119f,0.0114f,0.0108f,0.0104f,0.0099f,0.0095f,0.0091f,0.0087f,0.0083f,
    0.0080f,0.0077f,0.0074f,0.0071f,0.0068f,0.0065f,0.0062f,0.0060f,0.0058f,0.0055f,
    0.0053f,0.0050f,0.0049f,0.0047f,0.0045f,0.0044f,0.0042f,0.0040f,0.0039f,0.0038f,
    0.0036f,0.0034f,0.0033f,0.0032f,0.0031f,0.0030f,0.0029f,0.0028f,0.0027f,0.0026f,
    0.0025f,0.0024f,0.0023f,0.0022f,0.0021f,0.0021f,0.0020f,0.0019f,0.0018f,0.0018f,
    0.0017f,0.0017f,0.0016f,0.0016f,0.0015f,0.0015f,0.0014f,0.0014f,0.0013f,0.0013f,
    0.0013f,0.0012f,0.0012f,0.0011f,0.0011f,0.0011f,0.0010f,0.0010f,0.0010f,0.0009f
};

__device__ __forceinline__ float sig2(float x) {
    return __builtin_amdgcn_rcpf(1.0f + __builtin_amdgcn_exp2f(x));
}
__device__ __forceinline__ float tanh2(float x) {
    return fmaf(2.0f, __builtin_amdgcn_rcpf(1.0f + __builtin_amdgcn_exp2f(x)), -1.0f);
}
__device__ __forceinline__ unsigned short tb(float x) {          // truncate fp32 -> bf16
    return (unsigned short)(__float_as_uint(x) >> 16);
}
__device__ __forceinline__ float fb(unsigned short h) {
    return __uint_as_float(((unsigned)h) << 16);
}

// A[128 rows][32 k], row r = u*4+q, PRE-SCALED by sc(q) = -log2e (i,f,o) / -2log2e (g):
//   u<30,  k<30 : sc*W_hh1[(q*30+u)*30+k]
//   u<30,  k==30: sc*W_ih1[(q*30+u)*13+12]   (avg column; B k=30 slot = AVG[t])
//   u==30, k<30 : sc*W_ih2[q*30+k]           (LSTM2 input dot rides the same MFMA)
// ws layout (float*): ushort whi[4096] @0; ushort wlo @2048; float bconst[128] @4096
//                     float wih1f[128*12] @4224; u32 avgpk[121] @5760 (hi|lo<<16)
// R22: pack runs on 32 blocks (8192 threads) — the old 1-block version was a
// serial single-CU crawl that sat in the harness-metric gap (~46us between
// dispatch time and scored dur). Partitioned by global thread id; all writes
// disjoint -> ws bit-identical to the 1-block version.
__global__ void pack_weights(const float* __restrict__ w_ih1,
                             const float* __restrict__ w_hh1,
                             const float* __restrict__ b1,
                             const float* __restrict__ w_ih2,
                             const float* __restrict__ b2,
                             float* __restrict__ ws) {
    unsigned short* whi = (unsigned short*)ws;
    unsigned short* wlo = (unsigned short*)(ws + 2048);
    float* bconst = ws + 4096;
    float* wih1f  = ws + 4224;
    unsigned* avgpk = (unsigned*)(ws + 5760);
    const int gid  = blockIdx.x * 256 + threadIdx.x;
    const int gstr = gridDim.x * 256;
    for (int idx = gid; idx < 4096; idx += gstr) {
        const int T = idx >> 9, lane = (idx >> 3) & 63, j = idx & 7;
        const int r = 16 * T + (lane & 15);
        const int k = ((lane >> 4) & 3) * 8 + j;
        const int u = r >> 2, q = r & 3;
        const float sc = (q == 2) ? (-2.0f * LOG2E) : (-LOG2E);
        float v = 0.0f;
        if (u < 30) {
            if (k < 30)       v = w_hh1[(q * 30 + u) * 30 + k];
            else if (k == 30) v = w_ih1[(q * 30 + u) * 13 + 12];
        } else if (u == 30 && k < 30) {
            v = w_ih2[q * 30 + k];
        }
        v *= sc;
        const unsigned short hi = tb(v);
        whi[idx] = hi;
        wlo[idx] = tb(v - fb(hi));
    }
    for (int r = gid; r < 128; r += gstr) {
        const int u = r >> 2, q = r & 3;
        const float sc = (q == 2) ? (-2.0f * LOG2E) : (-LOG2E);
        bconst[r] = sc * ((u < 30) ? b1[q * 30 + u] : ((u == 30) ? b2[q] : 0.0f));
    }
    for (int idx = gid; idx < 1536; idx += gstr) {
        const int r = idx / 12, d = idx % 12;
        const int u = r >> 2, q = r & 3;
        const float sc = (q == 2) ? (-2.0f * LOG2E) : (-LOG2E);
        wih1f[idx] = (u < 30) ? sc * w_ih1[(q * 30 + u) * 13 + d] : 0.0f;
    }
    for (int t = gid; t < 121; t += gstr) {
        const float a = (t < 120) ? AVG_D[t] : 0.0f;
        const unsigned short hi = tb(a);
        const unsigned short lo = tb(a - fb(hi));
        avgpk[t] = (unsigned)hi | ((unsigned)lo << 16);
    }
}

// R20/R22 lstm kernel = R14, the measured optimum (199.8us steady; VALUBusy
// 67.6, MfmaUtil 21.0, VGPR 52, FETCH ~900KB). Post-R14 structural probes all
// regressed: R16 dual-group ILP 216.7 (same busy, more idle at 2w/SIMD),
// R17 4-wave split 205 (Occ 60% but idle unchanged — barrier-structural),
// R19 20/12 balance+fusion 219 (i-cache blowup: FETCH 890KB->4.7MB).
// Invariant: busy ~133us = trans-issue floor of this formulation (5 exp2 +
// ~1.5 rcp per cell @ ~16cyc/wave64); idle ~60us = per-step rendezvous
// shadow, insensitive to occupancy/ILP/balance. Structure: 2 waves/block,
// wave w owns tiles 4w..4w+3 (units 16w..16w+15; wave1 owns LSTM2 row u=30);
// hi/lo split LDS (stride 40 ushorts) -> B = 2 direct ds_read_b128, no
// perms; paired h-rcp with carg clamp +-20; unguarded cell math with
// store-patch for u>=30; one __syncthreads per step; avgpk prefetched.
__global__ __launch_bounds__(128, 4)
void lstm_mfma_kernel(const float* __restrict__ feat,
                      const float* __restrict__ w_hh2,
                      const float* __restrict__ ws,
                      float* __restrict__ out) {
    __shared__ __align__(16) unsigned short hhi[2][16 * 40];  // 2.5 KB x2 bufs
    __shared__ __align__(16) unsigned short hlo[2][16 * 40];  // 2.5 KB x2 bufs
    __shared__ __align__(16) float out_s[16 * 124];           // h2 staging 7.9 KB

    const int tid  = threadIdx.x;
    const int lane = tid & 63;
    const int wv   = __builtin_amdgcn_readfirstlane(tid >> 6) & 1;
    const int s    = lane & 15;
    const int quad = lane >> 4;
    const int seq  = blockIdx.x * 16 + s;
    const unsigned* avgpk = (const unsigned*)(ws + 5760);

    // zero both hi/lo buffers (pads stay 0)
    {
        unsigned* zh = (unsigned*)(&hhi[0][0]);
        unsigned* zl = (unsigned*)(&hlo[0][0]);
        for (int i = tid; i < 640; i += 128) { zh[i] = 0u; zl[i] = 0u; }
    }
    __syncthreads();
    if (tid < 16) {
        const unsigned a0 = avgpk[0];
        hhi[0][tid * 40 + 30] = (unsigned short)a0;          // hi half
        hlo[0][tid * 40 + 30] = (unsigned short)(a0 >> 16);  // lo half
    }

    // ---- A fragments: this wave's 4 tiles (Tg = 4*wv + T) ----
    bf16x8 Ahi[4], Alo[4];
    {
        const unsigned short* wahi = (const unsigned short*)ws;
        const unsigned short* walo = (const unsigned short*)(ws + 2048);
#pragma unroll
        for (int T = 0; T < 4; T++) {
            const int Tg = 4 * wv + T;
            Ahi[T] = *(const bf16x8*)(wahi + Tg * 512 + lane * 8);
            Alo[T] = *(const bf16x8*)(walo + Tg * 512 + lane * 8);
        }
    }

    // ---- per-sequence constant projection (scaled domain), 4 tiles ----
    float f0[12];
    {
        const float4* fp = reinterpret_cast<const float4*>(feat + seq * 12);
        float4 A = fp[0], B = fp[1], C = fp[2];
        f0[0]=A.x; f0[1]=A.y; f0[2]=A.z; f0[3]=A.w;
        f0[4]=B.x; f0[5]=B.y; f0[6]=B.z; f0[7]=B.w;
        f0[8]=C.x; f0[9]=C.y; f0[10]=C.z; f0[11]=C.w;
    }
    f32x4 projb[4];
    {
        const float* bconst = ws + 4096;
        const float* wih1f  = ws + 4224;
#pragma unroll
        for (int T = 0; T < 4; T++) {
#pragma unroll
            for (int g = 0; g < 4; g++) {
                const int r = 16 * (4 * wv + T) + 4 * quad + g;
                float acc = bconst[r];
#pragma unroll
                for (int d = 0; d < 12; d++) acc = fmaf(f0[d], wih1f[r * 12 + d], acc);
                projb[T][g] = acc;
            }
        }
    }

    float c1[4];
#pragma unroll
    for (int T = 0; T < 4; T++) c1[T] = 0.0f;
    float h2 = 0.0f, c2 = 0.0f;
    const float whs0 = -LOG2E * w_hh2[0];
    const float whs1 = -LOG2E * w_hh2[1];
    const float whs2 = -2.0f * LOG2E * w_hh2[2];
    const float whs3 = -LOG2E * w_hh2[3];

    __syncthreads();   // AVG seed visible to both waves

    unsigned apk_cur = avgpk[1];   // AVG slot value for the t=0 update

#pragma unroll 1
    for (int t = 0; t <= 120; t++) {
        const int buf = t & 1;
        const unsigned short* bh = hhi[buf];
        const unsigned short* bl = hlo[buf];
        unsigned short* nh = hhi[buf ^ 1];
        unsigned short* nl = hlo[buf ^ 1];

        // prefetch next AVG word a full iteration early (off the serial chain)
        const unsigned apk = apk_cur;
        apk_cur = avgpk[(t + 2 <= 120) ? (t + 2) : 120];

        // ---- B fragment: 2 direct ds_read_b128, NO perms ----
        const bf16x8 Bhi = *(const bf16x8*)(bh + s * 40 + 8 * quad);
        const bf16x8 Blo = *(const bf16x8*)(bl + s * 40 + 8 * quad);

        // ---- 12 MFMAs: D = Ahi*Bhi + Ahi*Blo + Alo*Bhi + projb ----
        f32x4 D[4];
#pragma unroll
        for (int T = 0; T < 4; T++)
            D[T] = __builtin_amdgcn_mfma_f32_16x16x32_bf16(Alo[T], Bhi, projb[T], 0, 0, 0);
#pragma unroll
        for (int T = 0; T < 4; T++)
            D[T] = __builtin_amdgcn_mfma_f32_16x16x32_bf16(Ahi[T], Blo, D[T], 0, 0, 0);
#pragma unroll
        for (int T = 0; T < 4; T++)
            D[T] = __builtin_amdgcn_mfma_f32_16x16x32_bf16(Ahi[T], Bhi, D[T], 0, 0, 0);

        // ---- LSTM2 cell for step t-1 (wave1 local tile3 = rows 120..123) ----
        if (wv == 1 && t >= 1 && quad == 2) {
            const float g0 = fmaf(h2, whs0, D[3][0]);
            const float g1 = fmaf(h2, whs1, D[3][1]);
            const float g2 = fmaf(h2, whs2, D[3][2]);
            const float g3 = fmaf(h2, whs3, D[3][3]);
            c2 = sig2(g1) * c2 + sig2(g0) * tanh2(g2);
            h2 = sig2(g3) * tanh2(c2 * (-2.0f * LOG2E));
            out_s[s * 124 + (t - 1)] = h2;
        }

        // ---- LSTM1 activations (u=16wv+4T+quad), UNGUARDED; paired h-rcp ----
        if (t < 120) {
            float s2a[4], Ba[4], hka[4];
#pragma unroll
            for (int T = 0; T < 4; T++) {
                const float ei = __builtin_amdgcn_exp2f(D[T][0]);
                const float ef = __builtin_amdgcn_exp2f(D[T][1]);
                const float eg = __builtin_amdgcn_exp2f(D[T][2]);
                const float eo = __builtin_amdgcn_exp2f(D[T][3]);
                const float pi_ = 1.0f + ei, pf = 1.0f + ef;
                const float pg  = 1.0f + eg, po = 1.0f + eo;
                const float pig = pi_ * pg;
                const float num = fmaf(c1[T], pig, (1.0f - eg) * pf);
                const float ck  = num * __builtin_amdgcn_rcpf(pf * pig);
                c1[T] = ck;
                float carg = -2.0f * LOG2E * ck;
                carg = fminf(fmaxf(carg, -20.0f), 20.0f);
                const float ec = __builtin_amdgcn_exp2f(carg);
                s2a[T] = 1.0f - ec;
                Ba[T]  = po * (1.0f + ec);
            }
            // paired reciprocals: (0,1) both always live; (2,3) T=3 may be dead
            {
                const float P01 = __builtin_amdgcn_rcpf(Ba[0] * Ba[1]);
                hka[0] = s2a[0] * (Ba[1] * P01);
                hka[1] = s2a[1] * (Ba[0] * P01);
                const int u3 = 16 * wv + 12 + quad;
                const float B3e = (u3 < 30) ? Ba[3] : 1.0f;
                const float P23 = __builtin_amdgcn_rcpf(Ba[2] * B3e);
                hka[2] = s2a[2] * (B3e * P23);
                hka[3] = s2a[3] * (Ba[2] * P23);
            }
#pragma unroll
            for (int T = 0; T < 4; T++) {
                const int u = 16 * wv + 4 * T + quad;
                const unsigned hbits = __float_as_uint(hka[T]);
                const float rem = hka[T] - __uint_as_float(hbits & 0xffff0000u);
                unsigned hi16 = hbits >> 16;
                unsigned lo16 = __float_as_uint(rem) >> 16;
                if (T == 3) {                       // only T=3 can hit u>=30
                    if (u == 30) { hi16 = apk & 0xffffu; lo16 = apk >> 16; }
                    else if (u == 31) { hi16 = 0u; lo16 = 0u; }
                }
                nh[s * 40 + u] = (unsigned short)hi16;
                nl[s * 40 + u] = (unsigned short)lo16;
            }
            __syncthreads();                        // h_t halves visible to both waves
        }
    }

    __syncthreads();
    // ---- coalesced flush: 16 seq x 120 t = 480 float4 by 128 threads ----
    float* outb = out + (size_t)blockIdx.x * 16 * 120;
#pragma unroll
    for (int it = 0; it < 4; it++) {
        const int fi = it * 128 + tid;
        if (fi < 480) {
            const int sq = fi / 30, j = fi % 30;
            const float4 v = *reinterpret_cast<const float4*>(&out_s[sq * 124 + j * 4]);
            *reinterpret_cast<float4*>(&outb[sq * 120 + j * 4]) = v;
        }
    }
}

extern "C" void kernel_launch(void* const* d_in, const int* in_sizes, int n_in,
                              void* d_out, int out_size, void* d_ws, size_t ws_size,
                              hipStream_t stream) {
    (void)in_sizes; (void)n_in; (void)out_size; (void)ws_size;
    const float* feat  = (const float*)d_in[0];
    const float* w_ih1 = (const float*)d_in[1];
    const float* w_hh1 = (const float*)d_in[2];
    const float* b1    = (const float*)d_in[3];
    const float* w_ih2 = (const float*)d_in[4];
    const float* w_hh2 = (const float*)d_in[5];
    const float* b2    = (const float*)d_in[6];
    float* ws  = (float*)d_ws;
    float* out = (float*)d_out;

    hipLaunchKernelGGL(pack_weights, dim3(32), dim3(256), 0, stream,
                       w_ih1, w_hh1, b1, w_ih2, b2, ws);
    hipLaunchKernelGGL(lstm_mfma_kernel, dim3(2048), dim3(128), 0, stream,
                       feat, w_hh2, ws, out);
}